// Round 10
// baseline (958.700 us; speedup 1.0000x reference)
//
#include <hip/hip_runtime.h>

// Problem constants (from reference): T=1024, B=32, D=768, L=48
#define T_ 1024
#define B_ 32
#define D_ 768
#define L_ 48
#define TB_ (T_ * B_)   // 32768 rows of the emissions GEMM

typedef __attribute__((ext_vector_type(4))) float f32x4;

// ---------------------------------------------------------------------------
// Kernel A: E = exp(feats @ W + b)   (fp32, M=32768 N=48 K=768)
// Evidence: four structurally different versions (tile size, dbuf,
// occupancy) all measured ~190 µs vs a ~20 µs floor; the common primitives
// were global_load_lds staging + 2-rows/thread blocking (DS:FMA ratio 4-5x
// on the per-CU-shared DS pipe).  This version:
//   - drops global_load_lds entirely: feats staged via float4 global loads
//     -> ds_write_b128 into a PADDED fbuf[64][68] (no swizzle needed;
//     compute reads conflict-free: 8 broadcast groups x 8 distinct
//     16B-slots covering all 32 banks).
//   - 4 rows x 6 cols per thread: per k4 = 10 DS-instr / 96 FMAs (was 8/48).
//   - 64-row tile, 128 threads (2 waves), grid 512 -> 2 blocks/CU: one
//     block's barrier/staging stalls hide under the other's compute.
// LDS = (64*68 + 48*68)*4 = 30.5 KB.
// ---------------------------------------------------------------------------
__global__ __launch_bounds__(128) void emis_gemm(
    const float* __restrict__ feats, const float* __restrict__ W,
    const float* __restrict__ bias, float* __restrict__ E) {
  __shared__ float fbuf[64 * 68];    // [row][k] padded +4
  __shared__ float wbuf[48 * 68];    // [j][ko] padded (2-way = free)
  const int tid = threadIdx.x;
  const int cg = tid & 7;            // col group -> cols c0..c0+5
  const int rg = tid >> 3;           // row group 0..15 -> rows rg+16i
  const int c0 = cg * 6;
  const int rowbase = blockIdx.x * 64;

  float acc[4][6];
#pragma unroll
  for (int i = 0; i < 4; i++)
#pragma unroll
    for (int c = 0; c < 6; c++) acc[i][c] = 0.f;

  for (int kc = 0; kc < D_; kc += 64) {
    __syncthreads();  // previous chunk's reads complete before overwrite

    // feats chunk 64x64: 8 float4 per thread, coalesced (16 lanes = one
    // 256B row segment), ds_write_b128 (rows 16B-aligned: stride 272B).
#pragma unroll
    for (int i = 0; i < 8; i++) {
      const int idx = tid + i * 128;   // 0..1023
      const int r = idx >> 4;          // 0..63
      const int ch = idx & 15;         // 0..15
      const float4 v =
          *(const float4*)(feats + (size_t)(rowbase + r) * D_ + kc + ch * 4);
      *(float4*)(fbuf + r * 68 + ch * 4) = v;
    }

    // W chunk transposed: wbuf[j][ko] = W[kc+ko][j] (coalesced reads)
#pragma unroll
    for (int i = 0; i < 24; i++) {
      const int idx = tid + i * 128;  // 0..3071
      const int ko = idx / 48;
      const int j = idx - ko * 48;
      wbuf[j * 68 + ko] = W[(kc + ko) * L_ + j];
    }

    __syncthreads();

#pragma unroll 4
    for (int k4 = 0; k4 < 16; k4++) {
      float4 fv[4];
      float4 wv4[6];
#pragma unroll
      for (int i = 0; i < 4; i++)
        fv[i] = *(const float4*)(fbuf + (rg + 16 * i) * 68 + k4 * 4);
#pragma unroll
      for (int cc = 0; cc < 6; cc++)
        wv4[cc] = *(const float4*)(wbuf + (c0 + cc) * 68 + k4 * 4);
#pragma unroll
      for (int i = 0; i < 4; i++) {
#pragma unroll
        for (int cc = 0; cc < 6; cc++) {
          acc[i][cc] = fmaf(fv[i].x, wv4[cc].x, acc[i][cc]);
          acc[i][cc] = fmaf(fv[i].y, wv4[cc].y, acc[i][cc]);
          acc[i][cc] = fmaf(fv[i].z, wv4[cc].z, acc[i][cc]);
          acc[i][cc] = fmaf(fv[i].w, wv4[cc].w, acc[i][cc]);
        }
      }
    }
  }

  // epilogue: E = exp(acc + bias), rows rg+16i, cols c0..c0+5
#pragma unroll
  for (int i = 0; i < 4; i++) {
    float* dst = E + (size_t)(rowbase + rg + 16 * i) * L_ + c0;
#pragma unroll
    for (int cc = 0; cc < 6; cc += 2) {
      float2 v;
      v.x = __expf(acc[i][cc + 0] + bias[c0 + cc + 0]);
      v.y = __expf(acc[i][cc + 1] + bias[c0 + cc + 1]);
      *(float2*)(dst + cc) = v;
    }
  }
}

// ---------------------------------------------------------------------------
// Kernel B: ONE WAVE PER BLOCK, one pass per block (grid = 2*B = 64 blocks
// <= 256 CUs -> private DS pipe per wave).  Scaled-probability recurrence.
// Round-8 evidence: the backend grants 64 VGPRs for this kernel shape
// (max-occupancy heuristic for tiny-LDS kernels) and P[48]+prefetch (~75
// regs demand) spilled -> 555 cyc/step at VALUBusy 2.2%.  Fix honors the
// 64-reg grant instead of fighting it:
//   - P SPLIT: k=0..31 in registers (32 regs), k=32..47 in LDS, k-major
//     pbuf[16][64] (lane j reads pbuf[kk][j]: stride-1 -> conflict-free
//     b32; constant data -> reads issue off the serial chain).  Reads go
//     through a VOLATILE pointer so LICM cannot hoist the 16 values back
//     into registers (which would re-create the spill).  True register
//     demand ~59 <= 64 -> zero spills.
//   - state broadcast via sbuf[2][64] parity double-buffer (12 broadcast
//     ds_read_b128 + 1 stride-1 ds_write_b32 per step, conflict-free).
//   - emission/tag prefetch depth 2 (E is L3-resident; 2 steps x ~350 cyc
//     covers the latency) -> only 8 prefetch regs.
//   - rescale (t%8==1) with zero cross-lane ops: m = max over the same
//     broadcast state reads (lane-uniform by construction), folded into
//     the step's emission multiply; logacc += log(m).  Worst unscaled
//     stretch <= 11 steps, far inside fp32 range.
//   - combine: atomicAdd(out+b, +/-logZ): exactly 2 commutative adds.
// Parity: state(t) lives in sbuf[t&1]; the step producing state t reads
// (t-1)&1, writes t&1.  2-step bodies keep t odd; tail <= 1 step.
// ---------------------------------------------------------------------------
__global__ __launch_bounds__(64) void crf_scan(
    const float* __restrict__ E, const int* __restrict__ tags,
    const int* __restrict__ lens, const float* __restrict__ begin,
    const float* __restrict__ trans, const float* __restrict__ endt,
    const int* __restrict__ bc, const int* __restrict__ ec,
    const int* __restrict__ tc, float* __restrict__ out) {
  __shared__ __align__(16) float sbuf[2][64];   // [parity][slot]
  __shared__ float pbuf[16][64];                // [k-32][j] lane-private P
  const int s = blockIdx.x;
  const int pass = s & 1;   // 0 = unconstrained fwd, 1 = constrained partial
  const int b = s >> 1;
  const int lane = threadIdx.x;
  const bool act = lane < L_;
  const bool par = (pass == 1);
  const int len = lens[b];            // in [512, 1024]
  const int stride = B_ * L_;
  const int base = b * L_ + (act ? lane : 0);  // clamped for lanes 48..63

  // P rows: k=0..31 in registers, k=32..47 in pbuf (zeros for lanes 48..63)
  float Pr[32];
#pragma unroll
  for (int k = 0; k < 32; k++) {
    float v = 0.f;
    if (act) {
      v = __expf(trans[lane * L_ + k]);
      if (par && tc[lane * L_ + k]) v = 0.f;
    }
    Pr[k] = v;
  }
#pragma unroll
  for (int kk = 0; kk < 16; kk++) {
    float v = 0.f;
    if (act) {
      v = __expf(trans[lane * L_ + 32 + kk]);
      if (par && tc[lane * L_ + 32 + kk]) v = 0.f;
    }
    pbuf[kk][lane] = v;
  }
  // volatile view for in-loop reads: blocks LICM from hoisting P into regs
  volatile const float* pv = &pbuf[0][0];

  // init: a0 = E[0]*exp(begin); partial pass additionally masked by bc/tags
  float a = 0.f;
  if (act) {
    a = E[base] * __expf(begin[lane]);
    if (par && (bc[lane] || tags[base])) a = 0.f;
  }
  float logacc = 0.f;

  sbuf[0][lane] = a;  // state(t=0) -> parity 0

  // Step producing state t (par_in = (t-1)&1).  resc: normalize by m = max
  // of the input state (from the same broadcast reads; lane-uniform).
  auto step = [&](int par_in, float ev, int tg, bool resc) {
    const f32x4* src = (const f32x4*)sbuf[par_in];
    float s0 = 0.f, s1 = 0.f, s2 = 0.f, s3 = 0.f;
    f32x4 mx = {0.f, 0.f, 0.f, 0.f};  // state is non-negative
#pragma unroll
    for (int c = 0; c < 8; c++) {
      const f32x4 q = src[c];
      if (resc) {
        mx.x = fmaxf(mx.x, q.x);
        mx.y = fmaxf(mx.y, q.y);
        mx.z = fmaxf(mx.z, q.z);
        mx.w = fmaxf(mx.w, q.w);
      }
      s0 = fmaf(q.x, Pr[4 * c + 0], s0);
      s1 = fmaf(q.y, Pr[4 * c + 1], s1);
      s2 = fmaf(q.z, Pr[4 * c + 2], s2);
      s3 = fmaf(q.w, Pr[4 * c + 3], s3);
    }
#pragma unroll
    for (int c = 8; c < 12; c++) {
      const f32x4 q = src[c];
      if (resc) {
        mx.x = fmaxf(mx.x, q.x);
        mx.y = fmaxf(mx.y, q.y);
        mx.z = fmaxf(mx.z, q.z);
        mx.w = fmaxf(mx.w, q.w);
      }
      const int kk = 4 * (c - 8);
      s0 = fmaf(q.x, pv[(kk + 0) * 64 + lane], s0);
      s1 = fmaf(q.y, pv[(kk + 1) * 64 + lane], s1);
      s2 = fmaf(q.z, pv[(kk + 2) * 64 + lane], s2);
      s3 = fmaf(q.w, pv[(kk + 3) * 64 + lane], s3);
    }
    float evp = ev;
    if (resc) {
      float m = fmaxf(fmaxf(mx.x, mx.y), fmaxf(mx.z, mx.w));
      m = fmaxf(m, 1e-30f);     // uniform across lanes (same broadcast data)
      logacc += __logf(m);
      evp = ev * (1.f / m);
    }
    float u = ((s0 + s1) + (s2 + s3)) * evp;
    if (tg) u = 0.f;  // tg is always 0 on the fwd pass
    a = u;
    sbuf[par_in ^ 1][lane] = u;  // publish for the next step
  };

  // preload emissions/tags for t = 1, 2 (len >= 512 so always valid)
  float e2[2];
  int tg2[2];
#pragma unroll
  for (int i = 0; i < 2; i++) {
    e2[i] = E[(size_t)(1 + i) * stride + base];
    tg2[i] = par ? tags[(size_t)(1 + i) * stride + base] : 0;
  }

  int t = 1;  // bodies keep t odd; rescale when t == 1 (mod 8)
  for (; t + 2 <= len; t += 2) {
    float p2[2];
    int q2[2];
#pragma unroll
    for (int i = 0; i < 2; i++) {
      int tt = t + 2 + i;
      tt = (tt < len) ? tt : (len - 1);
      p2[i] = E[(size_t)tt * stride + base];
      q2[i] = par ? tags[(size_t)tt * stride + base] : 0;
    }
    if ((t & 7) == 1) {
      step(0, e2[0], tg2[0], true);   // t odd -> input parity 0
    } else {
      step(0, e2[0], tg2[0], false);
    }
    step(1, e2[1], tg2[1], false);    // state t+1, input parity 1
    e2[0] = p2[0]; e2[1] = p2[1];
    tg2[0] = q2[0]; tg2[1] = q2[1];
  }
  // tail: one step iff t < len (t odd -> input parity 0)
  if (t < len) step(0, e2[0], tg2[0], false);

  // readout: logZ = logacc + log(sum_j a[j]*exp(end[j]))
  float z = 0.f;
  if (act) {
    float ez = __expf(endt[lane]);
    if (par && ec[lane]) ez = 0.f;
    z = a * ez;
  }
#pragma unroll
  for (int off = 32; off; off >>= 1) z += __shfl_xor(z, off, 64);
  const float logZ = logacc + __logf(z);
  if (lane == 0) atomicAdd(out + b, par ? -logZ : logZ);
}

// ---------------------------------------------------------------------------
extern "C" void kernel_launch(void* const* d_in, const int* in_sizes, int n_in,
                              void* d_out, int out_size, void* d_ws,
                              size_t ws_size, hipStream_t stream) {
  (void)in_sizes; (void)n_in; (void)out_size; (void)ws_size;
  const float* feats = (const float*)d_in[0];
  const int* tags = (const int*)d_in[1];
  const int* lens = (const int*)d_in[2];
  const float* W = (const float*)d_in[3];
  const float* bias = (const float*)d_in[4];
  const float* begin = (const float*)d_in[5];
  const float* trans = (const float*)d_in[6];
  const float* endt = (const float*)d_in[7];
  const int* bc = (const int*)d_in[8];
  const int* ec = (const int*)d_in[9];
  const int* tc = (const int*)d_in[10];

  float* E = (float*)d_ws;  // T*B*L floats = 6 MB scratch, exp(emissions)
  float* out = (float*)d_out;

  hipMemsetAsync(d_out, 0, B_ * sizeof(float), stream);

  emis_gemm<<<dim3(TB_ / 64), dim3(128), 0, stream>>>(feats, W, bias, E);
  crf_scan<<<dim3(2 * B_), dim3(64), 0, stream>>>(E, tags, lens, begin, trans,
                                                  endt, bc, ec, tc, out);
}

// Round 11
// 492.579 us; speedup vs baseline: 1.9463x; 1.9463x over previous
//
#include <hip/hip_runtime.h>

// Problem constants (from reference): T=1024, B=32, D=768, L=48
#define T_ 1024
#define B_ 32
#define D_ 768
#define L_ 48
#define TB_ (T_ * B_)   // 32768 rows of the emissions GEMM

typedef __attribute__((ext_vector_type(4))) float f32x4;

// ---------------------------------------------------------------------------
// Kernel A: E = exp(feats @ W + b)   (fp32, M=32768 N=48 K=768) — UNCHANGED
// from round 10 (reg-staged, no global_load_lds).  Deliberately frozen:
// (total - scan) has been 188-202 µs across FIVE structurally different
// GEMMs, so either an unmodeled external limit or harness overhead
// dominates.  With the scan fixed to ~140 µs this round, the counter table
// finally discriminates: emis_gemm appears at ~190 (real -> attack with
// counters next round) or stays absent (overhead-dominated).
// ---------------------------------------------------------------------------
__global__ __launch_bounds__(128) void emis_gemm(
    const float* __restrict__ feats, const float* __restrict__ W,
    const float* __restrict__ bias, float* __restrict__ E) {
  __shared__ float fbuf[64 * 68];    // [row][k] padded +4
  __shared__ float wbuf[48 * 68];    // [j][ko] padded (2-way = free)
  const int tid = threadIdx.x;
  const int cg = tid & 7;            // col group -> cols c0..c0+5
  const int rg = tid >> 3;           // row group 0..15 -> rows rg+16i
  const int c0 = cg * 6;
  const int rowbase = blockIdx.x * 64;

  float acc[4][6];
#pragma unroll
  for (int i = 0; i < 4; i++)
#pragma unroll
    for (int c = 0; c < 6; c++) acc[i][c] = 0.f;

  for (int kc = 0; kc < D_; kc += 64) {
    __syncthreads();  // previous chunk's reads complete before overwrite

    // feats chunk 64x64: 8 float4 per thread, coalesced (16 lanes = one
    // 256B row segment), ds_write_b128 (rows 16B-aligned: stride 272B).
#pragma unroll
    for (int i = 0; i < 8; i++) {
      const int idx = tid + i * 128;   // 0..1023
      const int r = idx >> 4;          // 0..63
      const int ch = idx & 15;         // 0..15
      const float4 v =
          *(const float4*)(feats + (size_t)(rowbase + r) * D_ + kc + ch * 4);
      *(float4*)(fbuf + r * 68 + ch * 4) = v;
    }

    // W chunk transposed: wbuf[j][ko] = W[kc+ko][j] (coalesced reads)
#pragma unroll
    for (int i = 0; i < 24; i++) {
      const int idx = tid + i * 128;  // 0..3071
      const int ko = idx / 48;
      const int j = idx - ko * 48;
      wbuf[j * 68 + ko] = W[(kc + ko) * L_ + j];
    }

    __syncthreads();

#pragma unroll 4
    for (int k4 = 0; k4 < 16; k4++) {
      float4 fv[4];
      float4 wv4[6];
#pragma unroll
      for (int i = 0; i < 4; i++)
        fv[i] = *(const float4*)(fbuf + (rg + 16 * i) * 68 + k4 * 4);
#pragma unroll
      for (int cc = 0; cc < 6; cc++)
        wv4[cc] = *(const float4*)(wbuf + (c0 + cc) * 68 + k4 * 4);
#pragma unroll
      for (int i = 0; i < 4; i++) {
#pragma unroll
        for (int cc = 0; cc < 6; cc++) {
          acc[i][cc] = fmaf(fv[i].x, wv4[cc].x, acc[i][cc]);
          acc[i][cc] = fmaf(fv[i].y, wv4[cc].y, acc[i][cc]);
          acc[i][cc] = fmaf(fv[i].z, wv4[cc].z, acc[i][cc]);
          acc[i][cc] = fmaf(fv[i].w, wv4[cc].w, acc[i][cc]);
        }
      }
    }
  }

  // epilogue: E = exp(acc + bias), rows rg+16i, cols c0..c0+5
#pragma unroll
  for (int i = 0; i < 4; i++) {
    float* dst = E + (size_t)(rowbase + rg + 16 * i) * L_ + c0;
#pragma unroll
    for (int cc = 0; cc < 6; cc += 2) {
      float2 v;
      v.x = __expf(acc[i][cc + 0] + bias[c0 + cc + 0]);
      v.y = __expf(acc[i][cc + 1] + bias[c0 + cc + 1]);
      *(float2*)(dst + cc) = v;
    }
  }
}

// ---------------------------------------------------------------------------
// Kernel B: ONE WAVE PER BLOCK, one pass per block (grid = 2*B = 64 blocks
// <= 256 CUs -> private DS pipe per wave).  Scaled-probability recurrence.
//
// Register evidence across rounds (the decisive pattern):
//   R4  __launch_bounds__(64)            -> VGPR 68  (= demand, no spill)
//   R5  __launch_bounds__(128, 1)        -> VGPR 64  (demand ~85 -> SPILL)
//   R8  lb(64)+amdgpu_waves_per_eu(1)    -> VGPR 64  (demand ~75 -> SPILL)
//   R10 __launch_bounds__(64) plain      -> VGPR 84  (= demand, no spill)
// => occupancy hints clamp the grant to 64 and force spills; PLAIN
//    launch_bounds follows demand.  R10's volatile-LDS P regressed 3.2x
//    (volatile serializes each ds_read at full latency) - reverted.
//
// This version: P[48] fully in registers, plain __launch_bounds__(64),
// prefetch depth 2 -> demand ~76 <= expected grant ~84 -> NO spills, NO
// volatile.  Per step: 1 stride-1 ds_write_b32 publish + 12 broadcast
// ds_read_b128 (conflict-free) + 48 FMAs in 4 chains: ~300-350 cyc.
//   - rescale (t%8==1) zero-cross-lane: m = max over the same broadcast
//     state reads (lane-uniform by construction), folded into the step's
//     emission multiply; logacc += log(m).  Worst unscaled stretch <= 11
//     steps, far inside fp32 range.
//   - combine: atomicAdd(out+b, +/-logZ): exactly 2 commutative adds.
// Parity: state(t) lives in sbuf[t&1]; the step producing state t reads
// (t-1)&1, writes t&1.  2-step bodies keep t odd; tail <= 1 step.
// ---------------------------------------------------------------------------
__global__ __launch_bounds__(64) void crf_scan(
    const float* __restrict__ E, const int* __restrict__ tags,
    const int* __restrict__ lens, const float* __restrict__ begin,
    const float* __restrict__ trans, const float* __restrict__ endt,
    const int* __restrict__ bc, const int* __restrict__ ec,
    const int* __restrict__ tc, float* __restrict__ out) {
  __shared__ __align__(16) float sbuf[2][64];   // [parity][slot]
  const int s = blockIdx.x;
  const int pass = s & 1;   // 0 = unconstrained fwd, 1 = constrained partial
  const int b = s >> 1;
  const int lane = threadIdx.x;
  const bool act = lane < L_;
  const bool par = (pass == 1);
  const int len = lens[b];            // in [512, 1024]
  const int stride = B_ * L_;
  const int base = b * L_ + (act ? lane : 0);  // clamped for lanes 48..63

  // Transition row fully in registers: P[k] = exp(trans[lane][k]); zero for
  // inactive lanes; constraint-masked on the partial pass.
  float P[L_];
#pragma unroll
  for (int k = 0; k < L_; k++) {
    float v = 0.f;
    if (act) {
      v = __expf(trans[lane * L_ + k]);
      if (par && tc[lane * L_ + k]) v = 0.f;
    }
    P[k] = v;
  }

  // init: a0 = E[0]*exp(begin); partial pass additionally masked by bc/tags
  float a = 0.f;
  if (act) {
    a = E[base] * __expf(begin[lane]);
    if (par && (bc[lane] || tags[base])) a = 0.f;
  }
  float logacc = 0.f;

  sbuf[0][lane] = a;  // state(t=0) -> parity 0

  // Step producing state t (par_in = (t-1)&1).  resc: normalize by m = max
  // of the input state (from the same broadcast reads; lane-uniform).
  auto step = [&](int par_in, float ev, int tg, bool resc) {
    const f32x4* src = (const f32x4*)sbuf[par_in];
    float s0 = 0.f, s1 = 0.f, s2 = 0.f, s3 = 0.f;
    f32x4 mx = {0.f, 0.f, 0.f, 0.f};  // state is non-negative
#pragma unroll
    for (int c = 0; c < 12; c++) {
      const f32x4 q = src[c];  // broadcast read: all lanes same address
      if (resc) {
        mx.x = fmaxf(mx.x, q.x);
        mx.y = fmaxf(mx.y, q.y);
        mx.z = fmaxf(mx.z, q.z);
        mx.w = fmaxf(mx.w, q.w);
      }
      s0 = fmaf(q.x, P[4 * c + 0], s0);
      s1 = fmaf(q.y, P[4 * c + 1], s1);
      s2 = fmaf(q.z, P[4 * c + 2], s2);
      s3 = fmaf(q.w, P[4 * c + 3], s3);
    }
    float evp = ev;
    if (resc) {
      float m = fmaxf(fmaxf(mx.x, mx.y), fmaxf(mx.z, mx.w));
      m = fmaxf(m, 1e-30f);     // uniform across lanes (same broadcast data)
      logacc += __logf(m);
      evp = ev * (1.f / m);
    }
    float u = ((s0 + s1) + (s2 + s3)) * evp;
    if (tg) u = 0.f;  // tg is always 0 on the fwd pass
    a = u;
    sbuf[par_in ^ 1][lane] = u;  // publish for the next step
  };

  // preload emissions/tags for t = 1, 2 (len >= 512 so always valid)
  float e2[2];
  int tg2[2];
#pragma unroll
  for (int i = 0; i < 2; i++) {
    e2[i] = E[(size_t)(1 + i) * stride + base];
    tg2[i] = par ? tags[(size_t)(1 + i) * stride + base] : 0;
  }

  int t = 1;  // bodies keep t odd; rescale when t == 1 (mod 8)
  for (; t + 2 <= len; t += 2) {
    float p2[2];
    int q2[2];
#pragma unroll
    for (int i = 0; i < 2; i++) {
      int tt = t + 2 + i;
      tt = (tt < len) ? tt : (len - 1);
      p2[i] = E[(size_t)tt * stride + base];
      q2[i] = par ? tags[(size_t)tt * stride + base] : 0;
    }
    if ((t & 7) == 1) {
      step(0, e2[0], tg2[0], true);   // t odd -> input parity 0
    } else {
      step(0, e2[0], tg2[0], false);
    }
    step(1, e2[1], tg2[1], false);    // state t+1, input parity 1
    e2[0] = p2[0]; e2[1] = p2[1];
    tg2[0] = q2[0]; tg2[1] = q2[1];
  }
  // tail: one step iff t < len (t odd -> input parity 0)
  if (t < len) step(0, e2[0], tg2[0], false);

  // readout: logZ = logacc + log(sum_j a[j]*exp(end[j]))
  float z = 0.f;
  if (act) {
    float ez = __expf(endt[lane]);
    if (par && ec[lane]) ez = 0.f;
    z = a * ez;
  }
#pragma unroll
  for (int off = 32; off; off >>= 1) z += __shfl_xor(z, off, 64);
  const float logZ = logacc + __logf(z);
  if (lane == 0) atomicAdd(out + b, par ? -logZ : logZ);
}

// ---------------------------------------------------------------------------
extern "C" void kernel_launch(void* const* d_in, const int* in_sizes, int n_in,
                              void* d_out, int out_size, void* d_ws,
                              size_t ws_size, hipStream_t stream) {
  (void)in_sizes; (void)n_in; (void)out_size; (void)ws_size;
  const float* feats = (const float*)d_in[0];
  const int* tags = (const int*)d_in[1];
  const int* lens = (const int*)d_in[2];
  const float* W = (const float*)d_in[3];
  const float* bias = (const float*)d_in[4];
  const float* begin = (const float*)d_in[5];
  const float* trans = (const float*)d_in[6];
  const float* endt = (const float*)d_in[7];
  const int* bc = (const int*)d_in[8];
  const int* ec = (const int*)d_in[9];
  const int* tc = (const int*)d_in[10];

  float* E = (float*)d_ws;  // T*B*L floats = 6 MB scratch, exp(emissions)
  float* out = (float*)d_out;

  hipMemsetAsync(d_out, 0, B_ * sizeof(float), stream);

  emis_gemm<<<dim3(TB_ / 64), dim3(128), 0, stream>>>(feats, W, bias, E);
  crf_scan<<<dim3(2 * B_), dim3(64), 0, stream>>>(E, tags, lens, begin, trans,
                                                  endt, bc, ec, tc, out);
}